// Round 3
// baseline (570.810 us; speedup 1.0000x reference)
//
#include <hip/hip_runtime.h>
#include <math.h>

// Problem constants
#define BATCH 64
#define LDIM  256
#define HDIM  1024
#define DDIM  1024
#define BAND  16
#define MNZ   33          // 2*BAND+1
#define NN    (DDIM*MNZ)  // 33792

typedef float v4f __attribute__((ext_vector_type(4)));

// ---------------------------------------------------------------------------
// K1: h = gelu(z @ W1 + b1), written TRANSPOSED: ht[k][b]  (k-major)
// ---------------------------------------------------------------------------
__global__ __launch_bounds__(256) void k1_h(const float* __restrict__ z,
                                            const float* __restrict__ W1,
                                            const float* __restrict__ b1,
                                            float* __restrict__ ht) {
    __shared__ float zs[LDIM];
    const int t = threadIdx.x;
    const int b = blockIdx.y;
    const int j = blockIdx.x * 256 + t;
    zs[t] = z[b * LDIM + t];
    __syncthreads();
    float acc = b1[j];
#pragma unroll 8
    for (int l = 0; l < LDIM; ++l)
        acc = fmaf(zs[l], W1[l * HDIM + j], acc);
    float g = 0.5f * acc * (1.0f + erff(acc * 0.70710678118654752f));
    ht[(size_t)j * BATCH + b] = g;
}

// ---------------------------------------------------------------------------
// K2: v = h @ W2 (+ b2 on slice 0), K split gridDim.y ways into partials.
// Block = 256 threads covering 256 cols x ALL 64 batches (W2 read exactly once).
// Thread: float4 of cols x 16 batches (64 accs). Wave-uniform h -> s_load.
// ---------------------------------------------------------------------------
__global__ __launch_bounds__(256) void k2_v(const float* __restrict__ W2,
                                            const float* __restrict__ b2,
                                            const float* __restrict__ ht,
                                            float* __restrict__ vpart,
                                            int kchunk) {
    const int lane = threadIdx.x & 63;
    const int wave = __builtin_amdgcn_readfirstlane((int)(threadIdx.x >> 6));
    const int c0 = blockIdx.x * 256 + lane * 4;
    const int b0 = wave * 16;
    const int ks = blockIdx.y * kchunk;

    v4f acc[16];
#pragma unroll
    for (int j = 0; j < 16; ++j) acc[j] = (v4f){0.f, 0.f, 0.f, 0.f};

    const float* __restrict__ wp = W2 + (size_t)ks * NN + c0;
    const float* __restrict__ hp = ht + (size_t)ks * BATCH + b0;  // wave-uniform

#pragma unroll 2
    for (int kk = 0; kk < kchunk; ++kk) {
        const v4f w4 = *(const v4f*)(wp + (size_t)kk * NN);
        const float* __restrict__ hh = hp + (size_t)kk * BATCH;
#pragma unroll
        for (int j = 0; j < 16; ++j)
            acc[j] += hh[j] * w4;
    }

    float* __restrict__ vo = vpart + (size_t)blockIdx.y * (BATCH * (size_t)NN)
                             + (size_t)b0 * NN + c0;
    if (blockIdx.y == 0) {
        const v4f bias = *(const v4f*)(b2 + c0);
#pragma unroll
        for (int j = 0; j < 16; ++j)
            *(v4f*)(vo + (size_t)j * NN) = acc[j] + bias;
    } else {
#pragma unroll
        for (int j = 0; j < 16; ++j)
            *(v4f*)(vo + (size_t)j * NN) = acc[j];
    }
}

// ---------------------------------------------------------------------------
// K3: out[b,i,j] = (|i-j|<=16) ? 0.5*(v[b,i,.]+v[b,j,.]) + (i==j) : 0
// v = sum of nsplit partial slices. 4 rows/block, float4 nontemporal stores.
// ---------------------------------------------------------------------------
__global__ __launch_bounds__(256) void k3_out(const float* __restrict__ vpart,
                                              float* __restrict__ out,
                                              int nsplit) {
    const int tid = threadIdx.x;
#pragma unroll
    for (int r = 0; r < 4; ++r) {
        const int rowid = blockIdx.x * 4 + r;
        const int b = rowid >> 10;
        const int i = rowid & (DDIM - 1);
        const int j0 = tid * 4;
        v4f res = (v4f){0.f, 0.f, 0.f, 0.f};
        if (j0 + 3 >= i - BAND && j0 <= i + BAND) {
            const int lo_i = (i > BAND) ? (i - BAND) : 0;
            const float* __restrict__ vb = vpart + (size_t)b * NN;
#pragma unroll
            for (int c = 0; c < 4; ++c) {
                const int j = j0 + c;
                const int d = j - i;
                float x = 0.0f;
                if (d >= -BAND && d <= BAND) {
                    const int lo_j = (j > BAND) ? (j - BAND) : 0;
                    float s = 0.0f;
                    for (int sN = 0; sN < nsplit; ++sN) {
                        const float* __restrict__ vs = vb + (size_t)sN * (BATCH * (size_t)NN);
                        s += vs[i * MNZ + (j - lo_i)] + vs[j * MNZ + (i - lo_j)];
                    }
                    x = 0.5f * s;
                    if (d == 0) x += 1.0f;
                }
                res[c] = x;
            }
        }
        v4f* dst = ((v4f*)out) + (size_t)rowid * (DDIM / 4) + tid;
        __builtin_nontemporal_store(res, dst);
    }
}

// ---------------------------------------------------------------------------
extern "C" void kernel_launch(void* const* d_in, const int* in_sizes, int n_in,
                              void* d_out, int out_size, void* d_ws, size_t ws_size,
                              hipStream_t stream) {
    const float* z  = (const float*)d_in[0];
    const float* W1 = (const float*)d_in[2];
    const float* b1 = (const float*)d_in[3];
    const float* W2 = (const float*)d_in[4];
    const float* b2 = (const float*)d_in[5];

    float* ht = (float*)d_ws;                 // 64*1024 floats
    float* vpart = ht + BATCH * HDIM;         // nsplit * 64*33792 floats
    float* out = (float*)d_out;

    // Pick the largest K-split whose partial buffers fit in the workspace.
    const size_t base = (size_t)BATCH * HDIM * sizeof(float);
    const size_t per_slice = (size_t)BATCH * NN * sizeof(float);
    int nsplit = 4;
    while (nsplit > 1 && base + (size_t)nsplit * per_slice > ws_size) nsplit >>= 1;
    const int kchunk = HDIM / nsplit;

    k1_h  <<<dim3(4, 64), 256, 0, stream>>>(z, W1, b1, ht);
    k2_v  <<<dim3(NN / 256, nsplit), 256, 0, stream>>>(W2, b2, ht, vpart, kchunk);
    k3_out<<<dim3((BATCH * DDIM) / 4), 256, 0, stream>>>(vpart, out, nsplit);
}

// Round 4
// 476.940 us; speedup vs baseline: 1.1968x; 1.1968x over previous
//
#include <hip/hip_runtime.h>
#include <math.h>

// Problem constants
#define BATCH 64
#define LDIM  256
#define HDIM  1024
#define DDIM  1024
#define BAND  16
#define MNZ   33          // 2*BAND+1
#define NN    (DDIM*MNZ)  // 33792
#define RTILE 64          // k3 rows per block
#define LSTR  34          // LDS row stride (pad 33->34: bank-conflict-free transposed reads)

typedef float v4f __attribute__((ext_vector_type(4)));

// ---------------------------------------------------------------------------
// K1: h = gelu(z @ W1 + b1), written TRANSPOSED: ht[k][b]  (k-major)
// ---------------------------------------------------------------------------
__global__ __launch_bounds__(256) void k1_h(const float* __restrict__ z,
                                            const float* __restrict__ W1,
                                            const float* __restrict__ b1,
                                            float* __restrict__ ht) {
    __shared__ float zs[LDIM];
    const int t = threadIdx.x;
    const int b = blockIdx.y;
    const int j = blockIdx.x * 256 + t;
    zs[t] = z[b * LDIM + t];
    __syncthreads();
    float acc = b1[j];
#pragma unroll 8
    for (int l = 0; l < LDIM; ++l)
        acc = fmaf(zs[l], W1[l * HDIM + j], acc);
    float g = 0.5f * acc * (1.0f + erff(acc * 0.70710678118654752f));
    ht[(size_t)j * BATCH + b] = g;
}

// ---------------------------------------------------------------------------
// K2: v = h @ W2 (+ b2 on slice 0), K split gridDim.y ways into partials.
// Block = 256 cols x ALL 64 batches (W2 read exactly once per slice).
// Thread: float4 of cols x 16 batches. Wave-uniform h base.
// ---------------------------------------------------------------------------
__global__ __launch_bounds__(256) void k2_v(const float* __restrict__ W2,
                                            const float* __restrict__ b2,
                                            const float* __restrict__ ht,
                                            float* __restrict__ vpart,
                                            int kchunk) {
    const int lane = threadIdx.x & 63;
    const int wave = __builtin_amdgcn_readfirstlane((int)(threadIdx.x >> 6));
    const int c0 = blockIdx.x * 256 + lane * 4;
    const int b0 = wave * 16;
    const int ks = blockIdx.y * kchunk;

    v4f acc[16];
#pragma unroll
    for (int j = 0; j < 16; ++j) acc[j] = (v4f){0.f, 0.f, 0.f, 0.f};

    const float* __restrict__ wp = W2 + (size_t)ks * NN + c0;
    const float* __restrict__ hp = ht + (size_t)ks * BATCH + b0;  // wave-uniform

#pragma unroll 2
    for (int kk = 0; kk < kchunk; ++kk) {
        const v4f w4 = *(const v4f*)(wp + (size_t)kk * NN);
        const float* __restrict__ hh = hp + (size_t)kk * BATCH;
#pragma unroll
        for (int j = 0; j < 16; ++j)
            acc[j] += hh[j] * w4;
    }

    float* __restrict__ vo = vpart + (size_t)blockIdx.y * (BATCH * (size_t)NN)
                             + (size_t)b0 * NN + c0;
    if (blockIdx.y == 0) {
        const v4f bias = *(const v4f*)(b2 + c0);
#pragma unroll
        for (int j = 0; j < 16; ++j)
            *(v4f*)(vo + (size_t)j * NN) = acc[j] + bias;
    } else {
#pragma unroll
        for (int j = 0; j < 16; ++j)
            *(v4f*)(vo + (size_t)j * NN) = acc[j];
    }
}

// ---------------------------------------------------------------------------
// K3: block = (batch b, 64-row tile). Stage v rows [i0-16, i0+80) flat into
// LDS (coalesced contiguous copy, summing nsplit slices), then write 64 full
// output rows with float4 nontemporal stores; band values read from LDS.
// ---------------------------------------------------------------------------
__global__ __launch_bounds__(256) void k3_out(const float* __restrict__ vpart,
                                              float* __restrict__ out,
                                              int nsplit) {
    const int tid  = threadIdx.x;
    const int tile = blockIdx.x & (DDIM / RTILE - 1);   // 16 row-tiles
    const int b    = blockIdx.x / (DDIM / RTILE);       // 64 batches
    const int i0 = tile * RTILE;
    const int js = (i0 >= BAND) ? (i0 - BAND) : 0;
    const int je = (i0 + RTILE + BAND <= DDIM) ? (i0 + RTILE + BAND) : DDIM;
    const int nelem = (je - js) * MNZ;                   // <= 3168

    __shared__ float ls[(RTILE + 2 * BAND) * LSTR];      // 96*34 floats = 12.75 KB

    const float* __restrict__ vb = vpart + (size_t)b * NN + (size_t)js * MNZ;
    const size_t slice = (size_t)BATCH * NN;
    for (int idx = tid; idx < nelem; idx += 256) {
        const int r = idx / MNZ;                // const-div -> magic mul
        const int m = idx - r * MNZ;
        float s = vb[idx];
        for (int sl = 1; sl < nsplit; ++sl)
            s += vb[(size_t)sl * slice + idx];
        ls[r * LSTR + m] = s;
    }
    __syncthreads();

    const int j0 = tid * 4;
    for (int r = 0; r < RTILE; ++r) {
        const int i = i0 + r;
        v4f res = (v4f){0.f, 0.f, 0.f, 0.f};
        if (j0 + 3 >= i - BAND && j0 <= i + BAND) {
            const int lo_i = (i > BAND) ? (i - BAND) : 0;
#pragma unroll
            for (int c = 0; c < 4; ++c) {
                const int j = j0 + c;
                const int d = j - i;
                float x = 0.0f;
                if (d >= -BAND && d <= BAND) {
                    const int lo_j = (j > BAND) ? (j - BAND) : 0;
                    x = 0.5f * (ls[(i - js) * LSTR + (j - lo_i)] +
                                ls[(j - js) * LSTR + (i - lo_j)]);
                    if (d == 0) x += 1.0f;
                }
                res[c] = x;
            }
        }
        v4f* dst = ((v4f*)out) + ((size_t)b * DDIM + i) * (DDIM / 4) + tid;
        __builtin_nontemporal_store(res, dst);
    }
}

// ---------------------------------------------------------------------------
extern "C" void kernel_launch(void* const* d_in, const int* in_sizes, int n_in,
                              void* d_out, int out_size, void* d_ws, size_t ws_size,
                              hipStream_t stream) {
    const float* z  = (const float*)d_in[0];
    const float* W1 = (const float*)d_in[2];
    const float* b1 = (const float*)d_in[3];
    const float* W2 = (const float*)d_in[4];
    const float* b2 = (const float*)d_in[5];

    float* ht = (float*)d_ws;                 // 64*1024 floats
    float* vpart = ht + BATCH * HDIM;         // nsplit * 64*33792 floats
    float* out = (float*)d_out;

    const size_t base = (size_t)BATCH * HDIM * sizeof(float);
    const size_t per_slice = (size_t)BATCH * NN * sizeof(float);
    int nsplit = 4;
    while (nsplit > 1 && base + (size_t)nsplit * per_slice > ws_size) nsplit >>= 1;
    const int kchunk = HDIM / nsplit;

    k1_h  <<<dim3(4, 64), 256, 0, stream>>>(z, W1, b1, ht);
    k2_v  <<<dim3(NN / 256, nsplit), 256, 0, stream>>>(W2, b2, ht, vpart, kchunk);
    k3_out<<<dim3(BATCH * (DDIM / RTILE)), 256, 0, stream>>>(vpart, out, nsplit);
}